// Round 1
// baseline (17820.316 us; speedup 1.0000x reference)
//
#include <hip/hip_runtime.h>
#include <math.h>

// FRNN: V=1024 visible, H=2048 hidden, F=3072 full, T=64 steps.
// Per step: U = lam .* (R @ W^T + b); U[:, :V] += (1-lam[:, :V]) .* x_t;  R = tanh(U)
// Output: diag(U_last[:, :V])  -> V floats.
#define V 1024
#define H 2048
#define F 3072
#define T 64

#define BM 64
#define BN 64
#define BK 16
// LDS pad of +4 keeps float4 (16B) alignment of rows while breaking pow2 strides.

__global__ __launch_bounds__(256)
void frnn_step(const float* __restrict__ Rin, const float* __restrict__ W,
               const float* __restrict__ b, const float* __restrict__ lam,
               const float* __restrict__ xt, float* __restrict__ Rout,
               float* __restrict__ out, int is_last)
{
    __shared__ float As[BK][BM + 4];  // As[k][m]
    __shared__ float Bs[BK][BN + 4];  // Bs[k][n]

    const int tid  = threadIdx.x;
    const int tx   = tid & 15;   // 16 col-groups
    const int ty   = tid >> 4;   // 16 row-groups
    const int row0 = blockIdx.y * BM;   // over V
    const int col0 = blockIdx.x * BN;   // over F

    // staging indices: each of 256 threads loads one float4 of A and one of B per k-tile
    const int lm = tid >> 2;         // 0..63  tile row
    const int lk = (tid & 3) * 4;    // 0,4,8,12

    float acc[4][4];
    #pragma unroll
    for (int i = 0; i < 4; ++i)
        #pragma unroll
        for (int j = 0; j < 4; ++j) acc[i][j] = 0.f;

    const float* aptr = &Rin[(row0 + lm) * F + lk];
    const float* bptr = &W  [(col0 + lm) * F + lk];

    for (int k0 = 0; k0 < F; k0 += BK) {
        float4 av = *reinterpret_cast<const float4*>(aptr + k0);
        float4 bv = *reinterpret_cast<const float4*>(bptr + k0);
        __syncthreads();   // previous iteration's reads done before overwrite
        As[lk + 0][lm] = av.x; As[lk + 1][lm] = av.y;
        As[lk + 2][lm] = av.z; As[lk + 3][lm] = av.w;
        Bs[lk + 0][lm] = bv.x; Bs[lk + 1][lm] = bv.y;
        Bs[lk + 2][lm] = bv.z; Bs[lk + 3][lm] = bv.w;
        __syncthreads();

        #pragma unroll
        for (int k = 0; k < BK; ++k) {
            float4 a  = *reinterpret_cast<const float4*>(&As[k][ty * 4]);
            float4 bb = *reinterpret_cast<const float4*>(&Bs[k][tx * 4]);
            float ar[4] = {a.x,  a.y,  a.z,  a.w};
            float br[4] = {bb.x, bb.y, bb.z, bb.w};
            #pragma unroll
            for (int i = 0; i < 4; ++i)
                #pragma unroll
                for (int j = 0; j < 4; ++j)
                    acc[i][j] = fmaf(ar[i], br[j], acc[i][j]);
        }
    }

    // epilogue: U = lam*(acc+b) + (1-lam)*x (visible cols), R = tanh(U)
    #pragma unroll
    for (int i = 0; i < 4; ++i) {
        const int gi = row0 + ty * 4 + i;          // < V
        #pragma unroll
        for (int j = 0; j < 4; ++j) {
            const int gj = col0 + tx * 4 + j;      // < F
            const float l = lam[gi * F + gj];
            float u = l * (acc[i][j] + b[gj]);
            if (gj < V) u += (1.f - l) * xt[gj];
            Rout[gi * F + gj] = tanhf(u);
            if (is_last && gi == gj) out[gi] = u;
        }
    }
}

extern "C" void kernel_launch(void* const* d_in, const int* in_sizes, int n_in,
                              void* d_out, int out_size, void* d_ws, size_t ws_size,
                              hipStream_t stream) {
    const float* X   = (const float*)d_in[0];   // T x V
    const float* W   = (const float*)d_in[1];   // F x F
    const float* b   = (const float*)d_in[2];   // F
    const float* lam = (const float*)d_in[3];   // V x F
    float* out = (float*)d_out;                 // V

    // Double-buffered R state in workspace: 2 * V*F floats = 25.2 MB
    float* Rbuf0 = (float*)d_ws;
    float* Rbuf1 = Rbuf0 + (size_t)V * F;

    // R0 = zeros (ws is poisoned 0xAA each call)
    hipMemsetAsync(Rbuf0, 0, (size_t)V * F * sizeof(float), stream);

    dim3 grid(F / BN, V / BM);   // 48 x 16 = 768 blocks
    dim3 block(256);
    for (int t = 0; t < T; ++t) {
        float* Rin  = (t & 1) ? Rbuf1 : Rbuf0;
        float* Rout = (t & 1) ? Rbuf0 : Rbuf1;
        frnn_step<<<grid, block, 0, stream>>>(Rin, W, b, lam, X + (size_t)t * V,
                                              Rout, out, (t == T - 1) ? 1 : 0);
    }
}

// Round 2
// 4315.841 us; speedup vs baseline: 4.1290x; 4.1290x over previous
//
#include <hip/hip_runtime.h>
#include <math.h>

// FRNN: V=1024, H=2048, F=3072, T=64.
// Per step: U = lam .* (R @ W^T + b); U[:, :V] += (1-lam_vis) .* x_t; R = tanh(U)
// Output: diag(U_last[:, :V]) -> V floats.
#define V 1024
#define H 2048
#define F 3072
#define T 64

#define BM 128
#define BN 128
#define BK 32   // one 16x16x32 MFMA K-slice per tile iteration

typedef _Float16 half8 __attribute__((ext_vector_type(8)));
typedef _Float16 half4 __attribute__((ext_vector_type(4)));
typedef float floatx4 __attribute__((ext_vector_type(4)));

__device__ __forceinline__ void gld16(const void* g, void* l) {
    __builtin_amdgcn_global_load_lds(
        (const __attribute__((address_space(1))) void*)g,
        (__attribute__((address_space(3))) void*)l, 16, 0, 0);
}

// ---- W fp32 -> fp16 conversion (once per launch) ----
__global__ __launch_bounds__(256)
void conv_w(const float* __restrict__ W, _Float16* __restrict__ W16, int n4) {
    int i = blockIdx.x * 256 + threadIdx.x;
    if (i < n4) {
        float4 v = reinterpret_cast<const float4*>(W)[i];
        half4 o = { (_Float16)v.x, (_Float16)v.y, (_Float16)v.z, (_Float16)v.w };
        reinterpret_cast<half4*>(W16)[i] = o;
    }
}

// ---- one recurrence step: C = Rin @ W16^T, fused epilogue ----
__global__ __launch_bounds__(512)
void frnn_step(const _Float16* __restrict__ Rin, const _Float16* __restrict__ W16,
               const float* __restrict__ b, const float* __restrict__ lam,
               const float* __restrict__ xt, _Float16* __restrict__ Rout,
               float* __restrict__ out, int is_last)
{
    // LDS tiles, [row][k] with 32 fp16 (64B) rows, NO padding (global_load_lds
    // forces lds = wave-uniform base + lane*16).
    __shared__ _Float16 As[BM * BK];  // R rows   (A: M x K)
    __shared__ _Float16 Bs[BN * BK];  // W rows   (B^T: rows are n, k-contiguous)

    const int tid  = threadIdx.x;
    const int lane = tid & 63;
    const int wid  = tid >> 6;         // 0..7
    const int wm   = wid & 1;          // 2 wave-rows (64 each)
    const int wn   = wid >> 1;         // 4 wave-cols (32 each)
    const int row0 = blockIdx.y * BM;  // over V
    const int col0 = blockIdx.x * BN;  // over F

    // staging map: thread t loads 16B chunk (row = t>>2, chunk = t&3)
    const int srow = tid >> 2;
    const int schunk = tid & 3;
    const _Float16* gA = Rin + (size_t)(row0 + srow) * F + schunk * 8;
    const _Float16* gB = W16 + (size_t)(col0 + srow) * F + schunk * 8;
    _Float16* lA = &As[tid * 8];   // tid*16 bytes: wave-contiguous by construction
    _Float16* lB = &Bs[tid * 8];

    // frag read offsets: A[m = lane&15][k = (lane>>4)*8 ...], same for B with n
    const int fr = lane & 15;
    const int fq = lane >> 4;

    floatx4 acc[4][2];
    #pragma unroll
    for (int i = 0; i < 4; ++i)
        #pragma unroll
        for (int j = 0; j < 2; ++j) acc[i][j] = (floatx4){0.f, 0.f, 0.f, 0.f};

    for (int k0 = 0; k0 < F; k0 += BK) {
        gld16(gA + k0, lA);
        gld16(gB + k0, lB);
        __syncthreads();   // drains vmcnt(0): staging complete

        half8 a[4], bb[2];
        #pragma unroll
        for (int i = 0; i < 4; ++i)
            a[i] = *reinterpret_cast<const half8*>(&As[(wm * 64 + i * 16 + fr) * BK + fq * 8]);
        #pragma unroll
        for (int j = 0; j < 2; ++j)
            bb[j] = *reinterpret_cast<const half8*>(&Bs[(wn * 32 + j * 16 + fr) * BK + fq * 8]);

        #pragma unroll
        for (int i = 0; i < 4; ++i)
            #pragma unroll
            for (int j = 0; j < 2; ++j)
                acc[i][j] = __builtin_amdgcn_mfma_f32_16x16x32_f16(a[i], bb[j], acc[i][j], 0, 0, 0);

        __syncthreads();   // reads done before next stage overwrites
    }

    // epilogue: C/D layout col = lane&15, row = (lane>>4)*4 + reg
    const int erow = (lane >> 4) * 4;
    const int ecol = lane & 15;
    #pragma unroll
    for (int i = 0; i < 4; ++i) {
        #pragma unroll
        for (int j = 0; j < 2; ++j) {
            const int gj = col0 + wn * 32 + j * 16 + ecol;
            const float bj = b[gj];
            const float xj = (gj < V) ? xt[gj] : 0.f;
            #pragma unroll
            for (int r = 0; r < 4; ++r) {
                const int gi = row0 + wm * 64 + i * 16 + erow + r;
                const float l = lam[(size_t)gi * F + gj];
                float u = l * (acc[i][j][r] + bj);
                if (gj < V) u += (1.f - l) * xj;
                Rout[(size_t)gi * F + gj] = (_Float16)tanhf(u);
                if (is_last && gi == gj) out[gi] = u;
            }
        }
    }
}

extern "C" void kernel_launch(void* const* d_in, const int* in_sizes, int n_in,
                              void* d_out, int out_size, void* d_ws, size_t ws_size,
                              hipStream_t stream) {
    const float* X   = (const float*)d_in[0];   // T x V
    const float* W   = (const float*)d_in[1];   // F x F
    const float* b   = (const float*)d_in[2];   // F
    const float* lam = (const float*)d_in[3];   // V x F
    float* out = (float*)d_out;                 // V

    // ws layout: W16 (F*F fp16) | R16 buf0 (V*F) | R16 buf1 (V*F)  = 31.5 MB
    _Float16* W16 = (_Float16*)d_ws;
    _Float16* R0  = W16 + (size_t)F * F;
    _Float16* R1  = R0 + (size_t)V * F;

    conv_w<<<(F * F / 4 + 255) / 256, 256, 0, stream>>>(W, W16, F * F / 4);
    hipMemsetAsync(R0, 0, (size_t)V * F * sizeof(_Float16), stream);

    dim3 grid(F / BN, V / BM);   // 24 x 8 = 192 blocks
    for (int t = 0; t < T; ++t) {
        _Float16* Rin  = (t & 1) ? R1 : R0;
        _Float16* Rout = (t & 1) ? R0 : R1;
        frnn_step<<<grid, dim3(512), 0, stream>>>(Rin, W16, b, lam, X + (size_t)t * V,
                                                  Rout, out, (t == T - 1) ? 1 : 0);
    }
}

// Round 3
// 2642.062 us; speedup vs baseline: 6.7449x; 1.6335x over previous
//
#include <hip/hip_runtime.h>
#include <math.h>

// FRNN: V=1024, H=2048, F=3072, T=64.
// Per step: U = lam .* (R @ W^T + b); U[:, :V] += (1-lam_vis) .* x_t; R = tanh(U)
// Output: diag(U_last[:, :V]) -> V floats.
#define V 1024
#define H 2048
#define F 3072
#define T 64

#define BM 128
#define BN 128
#define BK 32
#define ITER (F / BK)   // 96, divisible by 3

typedef _Float16 half8 __attribute__((ext_vector_type(8)));
typedef _Float16 half4 __attribute__((ext_vector_type(4)));
typedef float floatx4 __attribute__((ext_vector_type(4)));

__device__ __forceinline__ void gld16(const void* g, void* l) {
    __builtin_amdgcn_global_load_lds(
        (const __attribute__((address_space(1))) void*)g,
        (__attribute__((address_space(3))) void*)l, 16, 0, 0);
}

// ---- W fp32 -> fp16 conversion (once per launch) ----
__global__ __launch_bounds__(256)
void conv_w(const float* __restrict__ W, _Float16* __restrict__ W16, int n4) {
    int i = blockIdx.x * 256 + threadIdx.x;
    if (i < n4) {
        float4 v = reinterpret_cast<const float4*>(W)[i];
        half4 o = { (_Float16)v.x, (_Float16)v.y, (_Float16)v.z, (_Float16)v.w };
        reinterpret_cast<half4*>(W16)[i] = o;
    }
}

// fast tanh: 1 - 2/(e^{2u}+1); exact at +/-inf, ~1e-6 abs err (<< fp16 storage)
__device__ __forceinline__ float fast_tanh(float u) {
    float e = __expf(2.f * u);
    return 1.f - 2.f * __builtin_amdgcn_rcpf(e + 1.f);
}

// ---- one recurrence step: C = Rin @ W16^T, fused epilogue ----
__global__ __launch_bounds__(512)
void frnn_step(const _Float16* __restrict__ Rin, const _Float16* __restrict__ W16,
               const float* __restrict__ b, const float* __restrict__ lam,
               const float* __restrict__ xt, _Float16* __restrict__ Rout,
               float* __restrict__ out, int is_last)
{
    // 3-deep pipeline. SEPARATE objects so LLVM's LDS-DMA alias tracking can
    // issue precise (non-zero) vmcnt waits per buffer. No padding: gld16
    // requires lds addr = wave-uniform base + lane*16.
    __shared__ _Float16 As0[BM * BK], As1[BM * BK], As2[BM * BK];
    __shared__ _Float16 Bs0[BN * BK], Bs1[BN * BK], Bs2[BN * BK];

    const int tid  = threadIdx.x;
    const int lane = tid & 63;
    const int wid  = tid >> 6;         // 0..7
    const int wm   = wid & 1;          // 2 wave-rows (64 rows each)
    const int wn   = wid >> 1;         // 4 wave-cols (32 cols each)
    const int row0 = blockIdx.y * BM;  // over V
    const int col0 = blockIdx.x * BN;  // over F

    // staging map: thread t loads one 16B chunk of A and one of B per tile
    const int srow   = tid >> 2;
    const int schunk = tid & 3;
    const _Float16* gA = Rin + (size_t)(row0 + srow) * F + schunk * 8;
    const _Float16* gB = W16 + (size_t)(col0 + srow) * F + schunk * 8;
    const int loff = tid * 8;          // matches srow*BK + schunk*8

    // frag read coords
    const int fr = lane & 15;
    const int fq = lane >> 4;

    // ---- preload ALL epilogue operands into regs (oldest vmem ops; drained
    // by the first pipeline wait, fully hidden behind the K-loop) ----
    const int erow = (lane >> 4) * 4;
    const int ecol = lane & 15;
    const int gj0 = col0 + wn * 32 + ecol;        // j = 0 column
    const int gj1 = gj0 + 16;                     // j = 1 column
    float b_r[2] = { b[gj0], b[gj1] };
    float x_r[2] = { (gj0 < V) ? xt[gj0] : 0.f, (gj1 < V) ? xt[gj1] : 0.f };
    float lam_r[4][2][4];
    #pragma unroll
    for (int i = 0; i < 4; ++i) {
        #pragma unroll
        for (int r = 0; r < 4; ++r) {
            const int gi = row0 + wm * 64 + i * 16 + erow + r;
            lam_r[i][0][r] = lam[(size_t)gi * F + gj0];
            lam_r[i][1][r] = lam[(size_t)gi * F + gj1];
        }
    }

    floatx4 acc[4][2];
    #pragma unroll
    for (int i = 0; i < 4; ++i)
        #pragma unroll
        for (int j = 0; j < 2; ++j) acc[i][j] = (floatx4){0.f, 0.f, 0.f, 0.f};

    // ---- prologue: stage tiles 0 and 1 ----
    gld16(gA,      &As0[loff]);
    gld16(gB,      &Bs0[loff]);
    gld16(gA + BK, &As1[loff]);
    gld16(gB + BK, &Bs1[loff]);

    // Body: wait tile k (leave k+1 in flight) -> barrier -> read frags ->
    // prefetch k+2 -> MFMA. Barrier orders tile k-1 reads before k+2 writes.
#define BODY(CURA, CURB, NXA, NXB, KOFF)                                          \
    {                                                                             \
        asm volatile("s_waitcnt vmcnt(2)\n\ts_barrier" ::: "memory");             \
        half8 a[4], bb[2];                                                        \
        _Pragma("unroll")                                                         \
        for (int i = 0; i < 4; ++i)                                               \
            a[i] = *reinterpret_cast<const half8*>(                               \
                &CURA[(wm * 64 + i * 16 + fr) * BK + fq * 8]);                    \
        _Pragma("unroll")                                                         \
        for (int j = 0; j < 2; ++j)                                               \
            bb[j] = *reinterpret_cast<const half8*>(                              \
                &CURB[(wn * 32 + j * 16 + fr) * BK + fq * 8]);                    \
        int kp = (KOFF) + 2 * BK;                                                 \
        kp = (kp < F) ? kp : 0; /* tail wrap: harmless reload of tile 0 */        \
        gld16(gA + kp, &NXA[loff]);                                               \
        gld16(gB + kp, &NXB[loff]);                                               \
        _Pragma("unroll")                                                         \
        for (int i = 0; i < 4; ++i)                                               \
            _Pragma("unroll")                                                     \
            for (int j = 0; j < 2; ++j)                                           \
                acc[i][j] = __builtin_amdgcn_mfma_f32_16x16x32_f16(               \
                    a[i], bb[j], acc[i][j], 0, 0, 0);                             \
    }

    #pragma unroll 1
    for (int m = 0; m < ITER / 3; ++m) {
        const int k0 = m * 3 * BK;
        BODY(As0, Bs0, As2, Bs2, k0)
        BODY(As1, Bs1, As0, Bs0, k0 + BK)
        BODY(As2, Bs2, As1, Bs1, k0 + 2 * BK)
    }
#undef BODY

    // ---- epilogue: U = lam*(acc+b) + (1-lam)*x (visible cols), R = tanh(U) ----
    #pragma unroll
    for (int i = 0; i < 4; ++i) {
        const int gi_base = row0 + wm * 64 + i * 16 + erow;
        #pragma unroll
        for (int j = 0; j < 2; ++j) {
            const int gj = (j == 0) ? gj0 : gj1;
            #pragma unroll
            for (int r = 0; r < 4; ++r) {
                const int gi = gi_base + r;
                const float l = lam_r[i][j][r];
                float u = l * (acc[i][j][r] + b_r[j]);
                if (gj < V) u += (1.f - l) * x_r[j];
                Rout[(size_t)gi * F + gj] = (_Float16)fast_tanh(u);
                if (is_last && gi == gj) out[gi] = u;
            }
        }
    }
}

extern "C" void kernel_launch(void* const* d_in, const int* in_sizes, int n_in,
                              void* d_out, int out_size, void* d_ws, size_t ws_size,
                              hipStream_t stream) {
    const float* X   = (const float*)d_in[0];   // T x V
    const float* W   = (const float*)d_in[1];   // F x F
    const float* b   = (const float*)d_in[2];   // F
    const float* lam = (const float*)d_in[3];   // V x F
    float* out = (float*)d_out;                 // V

    // ws: W16 (F*F fp16) | R16 buf0 (V*F) | R16 buf1 (V*F) = 31.5 MB
    _Float16* W16 = (_Float16*)d_ws;
    _Float16* R0  = W16 + (size_t)F * F;
    _Float16* R1  = R0 + (size_t)V * F;

    conv_w<<<(F * F / 4 + 255) / 256, 256, 0, stream>>>(W, W16, F * F / 4);
    hipMemsetAsync(R0, 0, (size_t)V * F * sizeof(_Float16), stream);

    dim3 grid(F / BN, V / BM);   // 24 x 8 = 192 blocks; grid.x%8 pattern keeps
                                 // same-W blocks on one XCD (24 = 0 mod 8)
    for (int t = 0; t < T; ++t) {
        _Float16* Rin  = (t & 1) ? R1 : R0;
        _Float16* Rout = (t & 1) ? R0 : R1;
        frnn_step<<<grid, dim3(512), 0, stream>>>(Rin, W16, b, lam, X + (size_t)t * V,
                                                  Rout, out, (t == T - 1) ? 1 : 0);
    }
}